// Round 6
// baseline (24.805 us; speedup 1.0000x reference)
//
#include <hip/hip_runtime.h>

// SparseDualFlow closed form: out = K * relu(d), K from compile-time
// simulation of the 20-step momentum-prox recurrence (linear in state;
// ReLU never clamps for d>0, flow stays 0 for d<=0).
//
// This round: max MLP, zero-branch hot path. n4 = 2^22 float4s splits
// exactly into 2048 blocks x 256 threads x 8 float4/thread. All 8
// independent 16B loads issued back-to-back (128 B in flight per thread),
// then 8 nt stores. General n handled by a separate exact-fit split +
// tail kernel on the host side.

typedef float floatx4 __attribute__((ext_vector_type(4)));

constexpr float compute_K() {
    double a = 0.0, f = 0.0;
    for (int t = 0; t < 20; ++t) {
        const double am = 0.9 * a;
        const double g  = 2.0 * (f - am) - 1.0;   // gradient coeff of d
        a = am + 0.01 * g;
        f = f - a;                                 // relu never clamps for d>0
    }
    return (float)f;
}

#define UNROLL 8

// Exact-fit kernel: processes blocks of (256*UNROLL) float4s, no bounds checks.
__global__ __launch_bounds__(256) void sdf_main(const float* __restrict__ dd,
                                                float* __restrict__ out) {
    constexpr float K = compute_K();

    const floatx4* __restrict__ dd4  = reinterpret_cast<const floatx4*>(dd);
    floatx4* __restrict__       out4 = reinterpret_cast<floatx4*>(out);

    const int base = blockIdx.x * (256 * UNROLL) + threadIdx.x;

    floatx4 v[UNROLL];
    #pragma unroll
    for (int k = 0; k < UNROLL; ++k)
        v[k] = dd4[base + k * 256];           // 8 independent coalesced loads

    #pragma unroll
    for (int k = 0; k < UNROLL; ++k) {
        floatx4 o;
        o.x = K * fmaxf(v[k].x, 0.0f);
        o.y = K * fmaxf(v[k].y, 0.0f);
        o.z = K * fmaxf(v[k].z, 0.0f);
        o.w = K * fmaxf(v[k].w, 0.0f);
        __builtin_nontemporal_store(o, &out4[base + k * 256]);
    }
}

// Tail: scalar elements past the exact-fit region.
__global__ void sdf_tail(const float* __restrict__ dd, float* __restrict__ out,
                         int start, int n) {
    constexpr float K = compute_K();
    const int i = start + blockIdx.x * blockDim.x + threadIdx.x;
    if (i < n) out[i] = K * fmaxf(dd[i], 0.0f);
}

extern "C" void kernel_launch(void* const* d_in, const int* in_sizes, int n_in,
                              void* d_out, int out_size, void* d_ws, size_t ws_size,
                              hipStream_t stream) {
    const float* dd = (const float*)d_in[0];
    float* out      = (float*)d_out;
    const int n     = in_sizes[0];

    const int per_block = 256 * UNROLL * 4;         // scalar elems per block
    const int grid_main = n / per_block;            // 2048 at n = 2^24

    if (grid_main > 0)
        sdf_main<<<grid_main, 256, 0, stream>>>(dd, out);

    const int done = grid_main * per_block;
    if (done < n) {
        const int tail_n = n - done;
        sdf_tail<<<(tail_n + 255) / 256, 256, 0, stream>>>(dd, out, done, n);
    }
}